// Round 7
// baseline (3068.488 us; speedup 1.0000x reference)
//
#include <hip/hip_runtime.h>
#include <math.h>

// Problem constants (match setup_inputs in the reference).
#define B_SZ   32
#define T_SZ   400
#define D_SZ   2048
#define S_DEN  2000
#define E_DEN  60000
#define S_NUM  512
#define E_NUM  2048
#define DEN_C  1e-5f
#define NUM_C  1e-20f

#define P_CH   8          // den edge-chunks (CUs) per utterance
#define NTHR   512        // threads per block (8 waves)
#define EPT    16         // edges per thread (whole list lives in registers)
#define EPC    8192       // padded edges per chunk = NTHR*EPT

// ---- workspace layout (bytes). REC (prep only) overlaid by ANEWG (main only).
#define REC_OFF     0u          // int4[E_DEN] CSR {in,pdf,prob,out} sorted by out
#define ANEWG_OFF   0u          // float[B][2][2048] exchange buffer (524,288 B)
#define PACK_OFF    960000u     // uint2[P_CH*EPC] packed {in|pdf<<11|drow<<22, prob}
#define ROWPTR_OFF  1484288u    // int[S_DEN+1]
#define CNT_OFF     1492352u    // int[S_DEN]
#define CUR_OFF     1500352u    // int[S_DEN]
#define SROW_OFF    1508352u    // int[P_CH*NTHR] per-(chunk,thread) start row
#define RSPLIT_OFF  1524736u    // int[P_CH+1] chunk row splits
#define FLAG_OFF    1524800u    // int[B][8][16]: flag (b,p) on its own 64B line
#define CTR_OFF     1541184u    // int[B][16]: [1]=init ctr for XCD handshake
#define XCD_OFF     1543232u    // int[B][8] per-chunk XCC_ID
#define TOTD_OFF    1544256u    // float[B]
#define TOTN_OFF    1544384u    // float[B]
#define WS_BYTES    1544512u

__device__ __forceinline__ float expclip(float v) {
    return __expf(fminf(fmaxf(v, -30.f), 30.f));
}
// Agent-scope (device-coherent) accesses: relaxed atomics emit sc-bit
// write-through/bypass ops WITHOUT whole-L2 writeback (round-1 lesson:
// __threadfence costs a full L2 flush per call on gfx950). Empirically
// (r5/r6 absmax 0 with plain stores + agent reloads on same XCD) these
// loads observe dirty local-L2 lines, i.e. they are L2-local in latency.
__device__ __forceinline__ float ldf_agent(const float* p) {
    return __hip_atomic_load(p, __ATOMIC_RELAXED, __HIP_MEMORY_SCOPE_AGENT);
}
__device__ __forceinline__ int ldi_agent(const int* p) {
    return __hip_atomic_load(p, __ATOMIC_RELAXED, __HIP_MEMORY_SCOPE_AGENT);
}
__device__ __forceinline__ void stf_agent(float* p, float v) {
    __hip_atomic_store(p, v, __ATOMIC_RELAXED, __HIP_MEMORY_SCOPE_AGENT);
}
__device__ __forceinline__ void sti_agent(int* p, int v) {
    __hip_atomic_store(p, v, __ATOMIC_RELAXED, __HIP_MEMORY_SCOPE_AGENT);
}

// ---------------- prep kernels ----------------
__global__ void prep_init(char* ws) {
    int tid = threadIdx.x;
    int* cnt = (int*)(ws + CNT_OFF);
    int* cur = (int*)(ws + CUR_OFF);
    for (int i = tid; i < S_DEN; i += 256) { cnt[i] = 0; cur[i] = 0; }
    int* flags = (int*)(ws + FLAG_OFF);
    for (int i = tid; i < B_SZ * 8 * 16; i += 256) flags[i] = 0;
    int* ctr = (int*)(ws + CTR_OFF);
    for (int i = tid; i < B_SZ * 16; i += 256) ctr[i] = 0;
    int* xcd = (int*)(ws + XCD_OFF);
    if (tid < B_SZ * 8) xcd[tid] = 0;
}

__global__ void prep_hist(const int* __restrict__ e_out, char* ws) {
    int e = blockIdx.x * blockDim.x + threadIdx.x;
    if (e < E_DEN) atomicAdd((int*)(ws + CNT_OFF) + e_out[e], 1);
}

__global__ __launch_bounds__(1024) void prep_scan(char* ws) {
    __shared__ int sb[2][2048];
    const int* cnt = (const int*)(ws + CNT_OFF);
    int* rowp = (int*)(ws + ROWPTR_OFF);
    int tid = threadIdx.x;
    for (int i = tid; i < 2048; i += 1024) sb[0][i] = (i < S_DEN) ? cnt[i] : 0;
    __syncthreads();
    int cur = 0;
    for (int d = 1; d < 2048; d <<= 1) {
        for (int i = tid; i < 2048; i += 1024)
            sb[1 - cur][i] = sb[cur][i] + ((i >= d) ? sb[cur][i - d] : 0);
        __syncthreads();
        cur ^= 1;
    }
    if (tid == 0) rowp[0] = 0;
    for (int i = tid; i < S_DEN; i += 1024) rowp[i + 1] = sb[cur][i];
    __syncthreads();
    if (tid == 0) {
        // Row splits at ~equal edge counts: chunk p owns rows [rs[p], rs[p+1]).
        int* rs = (int*)(ws + RSPLIT_OFF);
        rs[0] = 0; rs[P_CH] = S_DEN;
        for (int p = 1; p < P_CH; ++p) {
            int target = (E_DEN / P_CH) * p;
            int lo = 0, hi = S_DEN;
            while (lo < hi) {
                int mid = (lo + hi) >> 1;
                int v = (mid == 0) ? 0 : sb[cur][mid - 1];   // rowp[mid]
                if (v >= target) hi = mid; else lo = mid + 1;
            }
            rs[p] = lo;
        }
    }
}

__global__ void prep_scatter(const int* __restrict__ e_in, const int* __restrict__ e_out,
                             const int* __restrict__ e_pdf, const float* __restrict__ e_prob,
                             char* ws) {
    int e = blockIdx.x * blockDim.x + threadIdx.x;
    if (e >= E_DEN) return;
    const int* rowp = (const int*)(ws + ROWPTR_OFF);
    int* cur = (int*)(ws + CUR_OFF);
    int4* recs = (int4*)(ws + REC_OFF);
    int o = e_out[e];
    int pos = rowp[o] + atomicAdd(&cur[o], 1);
    int4 r;
    r.x = e_in[e]; r.y = e_pdf[e];
    r.z = __float_as_int(e_prob[e]);
    r.w = o;
    recs[pos] = r;
}

// Pack per-chunk, padded to EPC with dummies (prob=0,d=0); srow per (chunk,thread).
__global__ void prep_pack(char* ws) {
    int slot = blockIdx.x * blockDim.x + threadIdx.x;
    if (slot >= P_CH * EPC) return;
    int p = slot >> 13;            // EPC = 8192
    int k = slot & (EPC - 1);
    const int* rowp = (const int*)(ws + ROWPTR_OFF);
    const int* rs = (const int*)(ws + RSPLIT_OFF);
    int ebase = rowp[rs[p]], eend = rowp[rs[p + 1]];
    uint2* pk = (uint2*)(ws + PACK_OFF);
    int idx = ebase + k;
    uint2 val;
    int myrow;
    if (idx < eend) {
        const int4* r4 = (const int4*)(ws + REC_OFF);
        int4 r = r4[idx];
        myrow = r.w;
        int nxt = (idx + 1 < eend) ? r4[idx + 1].w : myrow;  // chunk-last: d=0
        unsigned d = (unsigned)(nxt - myrow);
        if (d > 1023u) d = 1023u;                            // unreachable here
        val = make_uint2((unsigned)r.x | ((unsigned)r.y << 11) | (d << 22),
                         (unsigned)r.z);
    } else {
        val = make_uint2(0u, 0u);
        myrow = rs[p];
    }
    pk[slot] = val;
    if ((k & (EPT - 1)) == 0)
        ((int*)(ws + SROW_OFF))[(p << 9) + (k >> 4)] = myrow;
}

// ---------------- main kernel: 256 den blocks (32 utts x 8 chunks) -----------
// Leaky/main split: anew(t+1)[j] = inv(t)*Sum U[in]*prob*x  +  Sum lcp*x,
// where U = raw reloaded anew(t), lcp = DEN_C*leaky[in]*prob (constant).
// The leaky half + its xrow gathers (reused as next step's xv) run in the
// spin window; post-exchange critical path = 16 alpha gathers + FMAs only.
// alpha LDS holds RAW U (no rescale pass); busy-poll spin (no s_sleep).
__global__ __launch_bounds__(NTHR, 2) void chain_fwd8(
    const float* __restrict__ x, const int* __restrict__ lengths,
    const float* __restrict__ den_leaky, const float* __restrict__ den_final,
    const int* __restrict__ num_in, const int* __restrict__ num_out,
    const int* __restrict__ num_pdf, const float* __restrict__ num_prob,
    const float* __restrict__ num_leaky, const float* __restrict__ num_final,
    char* __restrict__ ws)
{
    __shared__ float alpha[2048];        // RAW U values (delta0 at t=0)
    __shared__ float xrow[2048];
    __shared__ float anew[2048];
    __shared__ float slc[2048];          // DEN_C * den_leaky (0 beyond S_DEN)
    __shared__ float nalpha[S_NUM];
    __shared__ float nanew[S_NUM];
    __shared__ float red[16];            // [0..7] den slice sums, [8..15] num
    __shared__ int   lcnt;               // monotonic intra-block arrive counter
    __shared__ int   sSame;
    extern __shared__ float dynpad[];    // occupancy pad (1 block/CU)
    const int tid = threadIdx.x;
    const int wid = tid >> 6;
    const int lane = tid & 63;
    if (lengths[0] == -12345) dynpad[tid] = 1.f;   // never true; keeps pad live

    const int b = blockIdx.x & (B_SZ - 1);
    const int p = blockIdx.x >> 5;
    const bool isNum = (p == 0);
    const int len = lengths[b];
    const float* xb = x + (size_t)b * T_SZ * D_SZ;
    const int* rs = (const int*)(ws + RSPLIT_OFF);
    const int rlo = rs[p], rhi = rs[p + 1];          // my produce slice
    const int rloW = rs[wid], rhiW = rs[wid + 1];    // my reload slice (per wave)
    float* anewg = (float*)(ws + ANEWG_OFF) + ((size_t)(b << 1) << 11);
    int* flags = (int*)(ws + FLAG_OFF);
    int* ctr = (int*)(ws + CTR_OFF) + (b << 4);
    int* xcdArr = (int*)(ws + XCD_OFF);
    int* myflag = &flags[((b << 3) + p) << 4];
    int* wflag  = &flags[((b << 3) + wid) << 4];

    if (tid == 0) lcnt = 0;

    // ---- pre-loop: XCD-group verification (one-time agent exchange) ----
    int myxcc = 0;
    asm volatile("s_getreg_b32 %0, hwreg(HW_REG_XCC_ID)" : "=s"(myxcc));
    if (tid == 0) {
        sti_agent(&xcdArr[(b << 3) + p], myxcc + 1);   // +1: distinguish from 0-init
        asm volatile("s_waitcnt vmcnt(0)" ::: "memory");
        __hip_atomic_fetch_add(ctr + 1, 1, __ATOMIC_RELAXED, __HIP_MEMORY_SCOPE_AGENT);
    }
    if (tid < 64) {
        int gd = 0;
        while (ldi_agent(ctr + 1) < P_CH) {
            __builtin_amdgcn_s_sleep(2);
            if (++gd > (1 << 16)) break;               // bail out instead of hanging
        }
        int v = (tid < 8) ? ldi_agent(&xcdArr[(b << 3) + tid]) : -1;
        int v0 = __shfl(v, 0, 64);
        bool eq = (tid < 8) ? (v == v0 && v != 0) : true;
        unsigned long long m = __ballot(eq);
        if (tid == 0) sSame = (~m == 0ULL) ? 1 : 0;
    }

    // ---- per-state constants + LDS init ----
    float fc[4];
    #pragma unroll
    for (int i = 0; i < 4; ++i) {
        int s = tid + (i << 9);
        float lv = (s < S_DEN) ? DEN_C * den_leaky[s] : 0.f;
        slc[s] = lv;
        fc[i] = (s < S_DEN) ? den_final[s] : 0.f;
        alpha[s] = (s == 0) ? 1.f : 0.f;               // RAW U0 = delta0 (inv=1)
        anew[s] = 0.f;
        xrow[s] = expclip(xb[s]);
    }

    // num state (chunk-0 blocks only); edges hoisted into registers.
    float nlk = 0.f, nfn = 0.f, nlogz = 0.f;
    int nein[4], neout[4], nepdf[4]; float neprb[4];
    if (isNum) {
        nlk = num_leaky[(b << 9) + tid];
        nfn = num_final[(b << 9) + tid];
        #pragma unroll
        for (int k = 0; k < 4; ++k) {
            int e = (b << 11) + tid + (k << 9);
            nein[k] = num_in[e]; neout[k] = num_out[e];
            nepdf[k] = num_pdf[e]; neprb[k] = num_prob[e];
        }
        nalpha[tid] = NUM_C * nlk + ((tid == 0) ? 1.f : 0.f);
        nanew[tid] = 0.f;
    }

    // Unpack the per-thread edge list once into registers.
    const uint4* __restrict__ pk4 = (const uint4*)(ws + PACK_OFF);
    const int qb = (p << 12) + (tid << 3);
    const uint4 c0 = pk4[qb + 0], c1 = pk4[qb + 1], c2 = pk4[qb + 2], c3 = pk4[qb + 3];
    const uint4 c4 = pk4[qb + 4], c5 = pk4[qb + 5], c6 = pk4[qb + 6], c7 = pk4[qb + 7];
    const unsigned w[16] = {c0.x, c0.z, c1.x, c1.z, c2.x, c2.z, c3.x, c3.z,
                            c4.x, c4.z, c5.x, c5.z, c6.x, c6.z, c7.x, c7.z};
    const float pf[16] = {
        __uint_as_float(c0.y), __uint_as_float(c0.w), __uint_as_float(c1.y), __uint_as_float(c1.w),
        __uint_as_float(c2.y), __uint_as_float(c2.w), __uint_as_float(c3.y), __uint_as_float(c3.w),
        __uint_as_float(c4.y), __uint_as_float(c4.w), __uint_as_float(c5.y), __uint_as_float(c5.w),
        __uint_as_float(c6.y), __uint_as_float(c6.w), __uint_as_float(c7.y), __uint_as_float(c7.w)};
    const int row0 = ((const int*)(ws + SROW_OFF))[(p << 9) + tid];
    float logz = 0.f;
    __syncthreads();                                   // LDS init + sSame ready
    const bool fastSt = (sSame != 0);

    // lcp_e = DEN_C*leaky[in_e]*prob_e (constant over t; slc gather once).
    float lcp[16];
    #pragma unroll
    for (int i = 0; i < 16; ++i) lcp[i] = slc[w[i] & 2047u] * pf[i];

    // Pre-loop leaky phase for step 0: xv gathers from xrow(0); accL -> anew.
    float xv[16];
    {
        #pragma unroll
        for (int i = 0; i < 16; ++i) xv[i] = xrow[(w[i] >> 11) & 2047u];
        float accL = 0.f; int row = row0;
        #pragma unroll
        for (int i = 0; i < 16; ++i) {
            accL = __fmaf_rn(lcp[i], xv[i], accL);
            const unsigned d = w[i] >> 22;
            if (d) { atomicAdd(&anew[row], accL); accL = 0.f; row += (int)d; }
        }
        if (accL != 0.f) atomicAdd(&anew[row], accL);
    }
    float inv = 1.f;                                   // U0 has asum=1

    for (int t = 0; t < len; ++t) {
        const int par = t & 1;
        // Prefetch x(t+1) into registers (consumed at stage).
        const int tn = (t + 1 < len) ? t + 1 : t;
        const float* xq = xb + (size_t)tn * D_SZ;
        const float xn0 = xq[tid], xn1 = xq[tid + 512];
        const float xn2 = xq[tid + 1024], xn3 = xq[tid + 1536];

        // ---- MAIN half: raw-alpha gathers; flush acc*inv at row boundaries ----
        {
            float av[16];
            #pragma unroll
            for (int i = 0; i < 16; ++i) av[i] = alpha[w[i] & 2047u];
            float acc = 0.f; int row = row0;
            #pragma unroll
            for (int i = 0; i < 16; ++i) {
                acc = __fmaf_rn(av[i] * pf[i], xv[i], acc);
                const unsigned d = w[i] >> 22;
                if (d) { atomicAdd(&anew[row], acc * inv); acc = 0.f; row += (int)d; }
            }
            if (acc != 0.f) atomicAdd(&anew[row], acc * inv);
        }
        __syncthreads();                         // B1: anew(t+1) complete

        // ---- publish slice; per-wave drain; LDS-arrive; last wave flags ----
        float* ag = anewg + (par << 11);
        if (fastSt) {
            for (int r = rlo + tid; r < rhi; r += NTHR) { ag[r] = anew[r]; anew[r] = 0.f; }
        } else {
            for (int r = rlo + tid; r < rhi; r += NTHR) { stf_agent(&ag[r], anew[r]); anew[r] = 0.f; }
        }
        asm volatile("s_waitcnt vmcnt(0)" ::: "memory");  // this wave's stores in L2
        if (lane == 0) {
            int old = atomicAdd(&lcnt, 1);
            if (old == 8 * t + 7) sti_agent(myflag, t + 1);   // all 8 waves drained
        }

        // ---- num step t (chunk 0 only; uses xrow(t), pre-restage) ----
        if (isNum) {
            #pragma unroll
            for (int k = 0; k < 4; ++k) {
                float v = nalpha[nein[k]] * neprb[k] * xrow[nepdf[k]];
                atomicAdd(&nanew[neout[k]], v);
            }
            __syncthreads();                     // Bnum: nanew complete
            float ps = nanew[tid];
            #pragma unroll
            for (int o = 32; o > 0; o >>= 1) ps += __shfl_down(ps, o, 64);
            if (lane == 0) red[8 + wid] = ps;
        }

        // Stage xrow(t+1).
        xrow[tid]        = expclip(xn0);
        xrow[tid + 512]  = expclip(xn1);
        xrow[tid + 1024] = expclip(xn2);
        xrow[tid + 1536] = expclip(xn3);
        __syncthreads();                         // Bx: anew zeroed + xrow(t+1) in

        // ---- leaky half of step t+1 (spin-window work; no inv needed) ----
        if (t + 1 < len) {
            #pragma unroll
            for (int i = 0; i < 16; ++i) xv[i] = xrow[(w[i] >> 11) & 2047u];
            float accL = 0.f; int row = row0;
            #pragma unroll
            for (int i = 0; i < 16; ++i) {
                accL = __fmaf_rn(lcp[i], xv[i], accL);
                const unsigned d = w[i] >> 22;
                if (d) { atomicAdd(&anew[row], accL); accL = 0.f; row += (int)d; }
            }
            if (accL != 0.f) atomicAdd(&anew[row], accL);
        }

        // ---- busy-poll spin on flag[wid]; reload slice wid raw into alpha ----
        {
            int gd = 0;
            while (ldi_agent(wflag) < t + 1) {
                if (++gd > (1 << 17)) break;     // bail out instead of hanging
            }
            float wsum = 0.f;
            for (int r = rloW + lane; r < rhiW; r += 64) {
                float an = ldf_agent(&ag[r]);
                alpha[r] = an;                   // RAW; inv folds into next flush
                wsum += an;
            }
            #pragma unroll
            for (int o = 32; o > 0; o >>= 1) wsum += __shfl_down(wsum, o, 64);
            if (lane == 0) red[wid] = wsum;
        }
        __syncthreads();                         // B2: all slices + sums in LDS

        const float asum = red[0]+red[1]+red[2]+red[3]+red[4]+red[5]+red[6]+red[7];
        inv = 1.f / asum;
        logz += logf(asum);
        if (isNum) {
            const float nasum = red[8]+red[9]+red[10]+red[11]
                              + red[12]+red[13]+red[14]+red[15];
            nalpha[tid] = __fmaf_rn(NUM_C * nlk, nasum, nanew[tid]) * (1.f / nasum);
            nanew[tid] = 0.f;
            nlogz += logf(nasum);
        }
        // next iteration's MAIN gathers read alpha (written pre-B2): no B3 needed
    }

    if (isNum) {   // chunk 0: den final dot (adash = U*inv + lc) + num final dot
        float fs = __fmaf_rn(alpha[tid], inv, slc[tid]) * fc[0]
                 + __fmaf_rn(alpha[tid + 512], inv, slc[tid + 512]) * fc[1]
                 + __fmaf_rn(alpha[tid + 1024], inv, slc[tid + 1024]) * fc[2]
                 + __fmaf_rn(alpha[tid + 1536], inv, slc[tid + 1536]) * fc[3];
        #pragma unroll
        for (int o = 32; o > 0; o >>= 1) fs += __shfl_down(fs, o, 64);
        if (lane == 0) red[wid] = fs;
        __syncthreads();
        if (tid == 0) {
            float tot = red[0]+red[1]+red[2]+red[3]+red[4]+red[5]+red[6]+red[7];
            ((float*)(ws + TOTD_OFF))[b] = logz + logf(tot);
        }
        __syncthreads();
        float nfs = nalpha[tid] * nfn;
        #pragma unroll
        for (int o = 32; o > 0; o >>= 1) nfs += __shfl_down(nfs, o, 64);
        if (lane == 0) red[wid] = nfs;
        __syncthreads();
        if (tid == 0) {
            float tot = red[0]+red[1]+red[2]+red[3]+red[4]+red[5]+red[6]+red[7];
            ((float*)(ws + TOTN_OFF))[b] = nlogz + logf(tot);
        }
    }
}

__global__ void combine2(const char* __restrict__ ws, const int* __restrict__ lengths,
                         float* __restrict__ out) {
    const float* totd = (const float*)(ws + TOTD_OFF);
    const float* totn = (const float*)(ws + TOTN_OFF);
    int tid = threadIdx.x;
    float v = 0.f, l = 0.f;
    if (tid < B_SZ) { v = totd[tid] - totn[tid]; l = (float)lengths[tid]; }
    #pragma unroll
    for (int o = 32; o > 0; o >>= 1) { v += __shfl_down(v, o, 64); l += __shfl_down(l, o, 64); }
    if (tid == 0) out[0] = v / l;
}

// ===================== round-1 fallback (used only if ws too small) ==========
__global__ __launch_bounds__(1024) void chain_fwd_kernel(
    const float* __restrict__ x, const int* __restrict__ lengths,
    const int* __restrict__ den_in, const int* __restrict__ den_out,
    const int* __restrict__ den_pdf, const float* __restrict__ den_prob,
    const float* __restrict__ den_leaky, const float* __restrict__ den_final,
    const int* __restrict__ num_in, const int* __restrict__ num_out,
    const int* __restrict__ num_pdf, const float* __restrict__ num_prob,
    const float* __restrict__ num_leaky, const float* __restrict__ num_final,
    float* __restrict__ part)
{
    __shared__ float xrow[D_SZ];
    __shared__ float alpha[S_DEN];
    __shared__ float anew[S_DEN];
    __shared__ float red[17];
    const int tid = threadIdx.x;
    const int nthr = 1024;
    const bool is_den = blockIdx.x < B_SZ;
    const int b = blockIdx.x & (B_SZ - 1);
    int S, E;
    const int *e_in, *e_out, *e_pdf;
    const float *e_prob, *leaky, *fin;
    float coeff;
    if (is_den) {
        S = S_DEN; E = E_DEN;
        e_in = den_in; e_out = den_out; e_pdf = den_pdf; e_prob = den_prob;
        leaky = den_leaky; fin = den_final; coeff = DEN_C;
    } else {
        S = S_NUM; E = E_NUM;
        e_in = num_in + b * E_NUM; e_out = num_out + b * E_NUM;
        e_pdf = num_pdf + b * E_NUM; e_prob = num_prob + b * E_NUM;
        leaky = num_leaky + b * S_NUM; fin = num_final + b * S_NUM;
        coeff = NUM_C;
    }
    const int len = lengths[b];
    const float* xb = x + (size_t)b * T_SZ * D_SZ;
    for (int s = tid; s < S; s += nthr)
        alpha[s] = coeff * leaky[s] + (s == 0 ? 1.0f : 0.0f);
    float logz = 0.0f;
    for (int t = 0; t < len; ++t) {
        for (int s = tid; s < S; s += nthr) anew[s] = 0.0f;
        const float* xt = xb + (size_t)t * D_SZ;
        for (int d = tid; d < D_SZ; d += nthr)
            xrow[d] = __expf(fminf(fmaxf(xt[d], -30.0f), 30.0f));
        __syncthreads();
        for (int e = tid; e < E; e += nthr) {
            float v = alpha[e_in[e]] * e_prob[e] * xrow[e_pdf[e]];
            atomicAdd(&anew[e_out[e]], v);
        }
        __syncthreads();
        float ps = 0.0f;
        for (int s = tid; s < S; s += nthr) ps += anew[s];
        #pragma unroll
        for (int off = 32; off > 0; off >>= 1) ps += __shfl_down(ps, off, 64);
        if ((tid & 63) == 0) red[tid >> 6] = ps;
        __syncthreads();
        if (tid < 64) {
            float v = (tid < 16) ? red[tid] : 0.0f;
            #pragma unroll
            for (int off = 8; off > 0; off >>= 1) v += __shfl_down(v, off, 64);
            if (tid == 0) red[16] = v;
        }
        __syncthreads();
        const float asum = red[16];
        const float inv = 1.0f / asum;
        for (int s = tid; s < S; s += nthr)
            alpha[s] = (anew[s] + coeff * leaky[s] * asum) * inv;
        logz += logf(asum);
        __syncthreads();
    }
    float fs = 0.0f;
    for (int s = tid; s < S; s += nthr) fs += alpha[s] * fin[s];
    #pragma unroll
    for (int off = 32; off > 0; off >>= 1) fs += __shfl_down(fs, off, 64);
    if ((tid & 63) == 0) red[tid >> 6] = fs;
    __syncthreads();
    if (tid < 64) {
        float v = (tid < 16) ? red[tid] : 0.0f;
        #pragma unroll
        for (int off = 8; off > 0; off >>= 1) v += __shfl_down(v, off, 64);
        if (tid == 0) part[blockIdx.x] = logz + logf(v);
    }
}

__global__ void combine_kernel(const float* __restrict__ part,
                               const int* __restrict__ lengths,
                               float* __restrict__ out)
{
    int tid = threadIdx.x;
    float v = 0.0f, l = 0.0f;
    if (tid < B_SZ) { v = part[tid] - part[B_SZ + tid]; l = (float)lengths[tid]; }
    #pragma unroll
    for (int off = 32; off > 0; off >>= 1) { v += __shfl_down(v, off, 64); l += __shfl_down(l, off, 64); }
    if (tid == 0) out[0] = v / l;
}

// ---------------------------------------------------------------------------
extern "C" void kernel_launch(void* const* d_in, const int* in_sizes, int n_in,
                              void* d_out, int out_size, void* d_ws, size_t ws_size,
                              hipStream_t stream)
{
    const float* x          = (const float*)d_in[0];
    const int*   lengths    = (const int*)  d_in[1];
    const int*   den_in_p   = (const int*)  d_in[2];
    const int*   den_out_p  = (const int*)  d_in[3];
    const int*   den_pdf_p  = (const int*)  d_in[4];
    const float* den_prob_p = (const float*)d_in[5];
    const float* den_leaky  = (const float*)d_in[6];
    const float* den_final  = (const float*)d_in[7];
    const int*   num_in_p   = (const int*)  d_in[8];
    const int*   num_out_p  = (const int*)  d_in[9];
    const int*   num_pdf_p  = (const int*)  d_in[10];
    const float* num_prob_p = (const float*)d_in[11];
    const float* num_leaky  = (const float*)d_in[12];
    const float* num_final  = (const float*)d_in[13];

    if (ws_size >= WS_BYTES) {
        char* ws = (char*)d_ws;
        hipLaunchKernelGGL(prep_init, dim3(1), dim3(256), 0, stream, ws);
        hipLaunchKernelGGL(prep_hist, dim3((E_DEN + 255) / 256), dim3(256), 0, stream,
                           den_out_p, ws);
        hipLaunchKernelGGL(prep_scan, dim3(1), dim3(1024), 0, stream, ws);
        hipLaunchKernelGGL(prep_scatter, dim3((E_DEN + 255) / 256), dim3(256), 0, stream,
                           den_in_p, den_out_p, den_pdf_p, den_prob_p, ws);
        hipLaunchKernelGGL(prep_pack, dim3((P_CH * EPC + 255) / 256), dim3(256), 0, stream, ws);
        // ~36.3 KB static + 45 KB pad > 80 KB -> one block/CU; 256 blocks on
        // 256 CUs, all co-resident (spin-safe), private LDS pipes.
        hipLaunchKernelGGL(chain_fwd8, dim3(P_CH * B_SZ), dim3(NTHR), 46080, stream,
                           x, lengths, den_leaky, den_final,
                           num_in_p, num_out_p, num_pdf_p, num_prob_p,
                           num_leaky, num_final, ws);
        hipLaunchKernelGGL(combine2, dim3(1), dim3(64), 0, stream,
                           ws, lengths, (float*)d_out);
    } else {
        float* part = (float*)d_ws;
        hipLaunchKernelGGL(chain_fwd_kernel, dim3(2 * B_SZ), dim3(1024), 0, stream,
                           x, lengths,
                           den_in_p, den_out_p, den_pdf_p, den_prob_p, den_leaky, den_final,
                           num_in_p, num_out_p, num_pdf_p, num_prob_p, num_leaky, num_final,
                           part);
        hipLaunchKernelGGL(combine_kernel, dim3(1), dim3(64), 0, stream,
                           part, lengths, (float*)d_out);
    }
}

// Round 8
// 2708.716 us; speedup vs baseline: 1.1328x; 1.1328x over previous
//
#include <hip/hip_runtime.h>
#include <math.h>

// Problem constants (match setup_inputs in the reference).
#define B_SZ   32
#define T_SZ   400
#define D_SZ   2048
#define S_DEN  2000
#define E_DEN  60000
#define S_NUM  512
#define E_NUM  2048
#define DEN_C  1e-5f
#define NUM_C  1e-20f

#define P_CH   8          // den edge-chunks (CUs) per utterance
#define NTHR   512        // threads per block (8 waves)
#define EPT    16         // edges per thread (whole list lives in 8 VGPR uint4s)
#define EPC    8192       // padded edges per chunk = NTHR*EPT

// ---- workspace layout (bytes). REC (prep only) overlaid by ANEWG (main only).
#define REC_OFF     0u          // int4[E_DEN] CSR {in,pdf,prob,out} sorted by out
#define ANEWG_OFF   0u          // float[B][2][2048] exchange buffer (524,288 B)
#define PACK_OFF    960000u     // uint2[P_CH*EPC] packed {in|pdf<<11|drow<<22, prob}
#define ROWPTR_OFF  1484288u    // int[S_DEN+1]
#define CNT_OFF     1492352u    // int[S_DEN]
#define CUR_OFF     1500352u    // int[S_DEN]
#define SROW_OFF    1508352u    // int[P_CH*NTHR] per-(chunk,thread) start row
#define RSPLIT_OFF  1524736u    // int[P_CH+1] chunk row splits
#define PSUM_OFF    1524800u    // float[B][2][16] partial asums (64B lines)
#define CTR_OFF     1528896u    // int[B][16]: [0]=arrive ctr, [1]=init ctr
#define XCD_OFF     1530944u    // int[B][8] per-chunk XCC_ID
#define TOTD_OFF    1531968u    // float[B]
#define TOTN_OFF    1532096u    // float[B]
#define WS_BYTES    1532224u

__device__ __forceinline__ float expclip(float v) {
    return __expf(fminf(fmaxf(v, -30.f), 30.f));
}
// Agent-scope (device-coherent) accesses: relaxed atomics emit sc-bit
// write-through/bypass ops WITHOUT whole-L2 writeback (round-1 lesson:
// __threadfence costs a full L2 flush per call on gfx950).
__device__ __forceinline__ float ldf_agent(const float* p) {
    return __hip_atomic_load(p, __ATOMIC_RELAXED, __HIP_MEMORY_SCOPE_AGENT);
}
__device__ __forceinline__ int ldi_agent(const int* p) {
    return __hip_atomic_load(p, __ATOMIC_RELAXED, __HIP_MEMORY_SCOPE_AGENT);
}
__device__ __forceinline__ void stf_agent(float* p, float v) {
    __hip_atomic_store(p, v, __ATOMIC_RELAXED, __HIP_MEMORY_SCOPE_AGENT);
}
__device__ __forceinline__ void sti_agent(int* p, int v) {
    __hip_atomic_store(p, v, __ATOMIC_RELAXED, __HIP_MEMORY_SCOPE_AGENT);
}

// ---------------- prep kernels ----------------
__global__ void prep_init(char* ws) {
    int tid = threadIdx.x;
    int* cnt = (int*)(ws + CNT_OFF);
    int* cur = (int*)(ws + CUR_OFF);
    for (int i = tid; i < S_DEN; i += 256) { cnt[i] = 0; cur[i] = 0; }
    int* ctr = (int*)(ws + CTR_OFF);
    for (int i = tid; i < B_SZ * 16; i += 256) ctr[i] = 0;
    int* xcd = (int*)(ws + XCD_OFF);
    if (tid < B_SZ * 8) xcd[tid] = 0;
}

__global__ void prep_hist(const int* __restrict__ e_out, char* ws) {
    int e = blockIdx.x * blockDim.x + threadIdx.x;
    if (e < E_DEN) atomicAdd((int*)(ws + CNT_OFF) + e_out[e], 1);
}

__global__ __launch_bounds__(1024) void prep_scan(char* ws) {
    __shared__ int sb[2][2048];
    const int* cnt = (const int*)(ws + CNT_OFF);
    int* rowp = (int*)(ws + ROWPTR_OFF);
    int tid = threadIdx.x;
    for (int i = tid; i < 2048; i += 1024) sb[0][i] = (i < S_DEN) ? cnt[i] : 0;
    __syncthreads();
    int cur = 0;
    for (int d = 1; d < 2048; d <<= 1) {
        for (int i = tid; i < 2048; i += 1024)
            sb[1 - cur][i] = sb[cur][i] + ((i >= d) ? sb[cur][i - d] : 0);
        __syncthreads();
        cur ^= 1;
    }
    if (tid == 0) rowp[0] = 0;
    for (int i = tid; i < S_DEN; i += 1024) rowp[i + 1] = sb[cur][i];
    __syncthreads();
    if (tid == 0) {
        // Row splits at ~equal edge counts: chunk p owns rows [rs[p], rs[p+1]),
        // i.e. a contiguous, disjoint edge range (edges sorted by out).
        int* rs = (int*)(ws + RSPLIT_OFF);
        rs[0] = 0; rs[P_CH] = S_DEN;
        for (int p = 1; p < P_CH; ++p) {
            int target = (E_DEN / P_CH) * p;
            int lo = 0, hi = S_DEN;
            while (lo < hi) {
                int mid = (lo + hi) >> 1;
                int v = (mid == 0) ? 0 : sb[cur][mid - 1];   // rowp[mid]
                if (v >= target) hi = mid; else lo = mid + 1;
            }
            rs[p] = lo;
        }
    }
}

__global__ void prep_scatter(const int* __restrict__ e_in, const int* __restrict__ e_out,
                             const int* __restrict__ e_pdf, const float* __restrict__ e_prob,
                             char* ws) {
    int e = blockIdx.x * blockDim.x + threadIdx.x;
    if (e >= E_DEN) return;
    const int* rowp = (const int*)(ws + ROWPTR_OFF);
    int* cur = (int*)(ws + CUR_OFF);
    int4* recs = (int4*)(ws + REC_OFF);
    int o = e_out[e];
    int pos = rowp[o] + atomicAdd(&cur[o], 1);
    int4 r;
    r.x = e_in[e]; r.y = e_pdf[e];
    r.z = __float_as_int(e_prob[e]);
    r.w = o;
    recs[pos] = r;
}

// Pack per-chunk, padded to EPC with dummies (prob=0,d=0); srow per (chunk,thread).
__global__ void prep_pack(char* ws) {
    int slot = blockIdx.x * blockDim.x + threadIdx.x;
    if (slot >= P_CH * EPC) return;
    int p = slot >> 13;            // EPC = 8192
    int k = slot & (EPC - 1);
    const int* rowp = (const int*)(ws + ROWPTR_OFF);
    const int* rs = (const int*)(ws + RSPLIT_OFF);
    int ebase = rowp[rs[p]], eend = rowp[rs[p + 1]];
    uint2* pk = (uint2*)(ws + PACK_OFF);
    int idx = ebase + k;
    uint2 val;
    int myrow;
    if (idx < eend) {
        const int4* r4 = (const int4*)(ws + REC_OFF);
        int4 r = r4[idx];
        myrow = r.w;
        int nxt = (idx + 1 < eend) ? r4[idx + 1].w : myrow;  // chunk-last: d=0
        unsigned d = (unsigned)(nxt - myrow);
        if (d > 1023u) d = 1023u;                            // unreachable here
        val = make_uint2((unsigned)r.x | ((unsigned)r.y << 11) | (d << 22),
                         (unsigned)r.z);
    } else {
        val = make_uint2(0u, 0u);
        myrow = rs[p];
    }
    pk[slot] = val;
    if ((k & (EPT - 1)) == 0)
        ((int*)(ws + SROW_OFF))[(p << 9) + (k >> 4)] = myrow;
}

// ---------------- main kernel: 256 den blocks (32 utts x 8 chunks) -----------
// Round-5 structure (best measured: chain 2569 us) with ONE change: the group
// barrier arrive is per-CHUNK (8 agent RMWs/step) instead of per-WAVE (64 RMWs
// to one L2 line/step, which serialize at the L2 atomic unit). Waves arrive on
// an LDS counter after their own vmcnt(0) drain; the last wave of the chunk
// does the single agent RMW. Spin target = 8*(t+1).
__global__ __launch_bounds__(NTHR, 2) void chain_fwd9(
    const float* __restrict__ x, const int* __restrict__ lengths,
    const float* __restrict__ den_leaky, const float* __restrict__ den_final,
    const int* __restrict__ num_in, const int* __restrict__ num_out,
    const int* __restrict__ num_pdf, const float* __restrict__ num_prob,
    const float* __restrict__ num_leaky, const float* __restrict__ num_final,
    char* __restrict__ ws)
{
    __shared__ float alpha[2048];
    __shared__ float xrow[2048];
    __shared__ float anew[2048];
    __shared__ float nalpha[S_NUM];
    __shared__ float nanew[S_NUM];
    __shared__ float red[24];
    __shared__ int   lcnt;               // monotonic intra-block arrive counter
    __shared__ int   sSame;
    extern __shared__ float dynpad[];    // 56 KB occupancy pad (1 block/CU)
    const int tid = threadIdx.x;
    const int lane = tid & 63;
    if (lengths[0] == -12345) dynpad[tid] = 1.f;   // never true; keeps pad live

    const int b = blockIdx.x & (B_SZ - 1);
    const int p = blockIdx.x >> 5;
    const bool isNum = (p == 0);
    const int len = lengths[b];
    const float* xb = x + (size_t)b * T_SZ * D_SZ;
    const int* rs = (const int*)(ws + RSPLIT_OFF);
    const int rlo = rs[p], rhi = rs[p + 1];
    float* anewg = (float*)(ws + ANEWG_OFF) + ((size_t)(b << 1) << 11);
    float* psumg = (float*)(ws + PSUM_OFF);
    int* ctr = (int*)(ws + CTR_OFF) + (b << 4);
    int* xcdArr = (int*)(ws + XCD_OFF);

    if (tid == 0) lcnt = 0;

    // ---- pre-loop: XCD-group verification (one-time agent exchange) ----
    int myxcc = 0;
    asm volatile("s_getreg_b32 %0, hwreg(HW_REG_XCC_ID)" : "=s"(myxcc));
    if (tid == 0) {
        sti_agent(&xcdArr[(b << 3) + p], myxcc + 1);   // +1: distinguish from 0-init
        asm volatile("s_waitcnt vmcnt(0)" ::: "memory");
        __hip_atomic_fetch_add(ctr + 1, 1, __ATOMIC_RELAXED, __HIP_MEMORY_SCOPE_AGENT);
    }
    if (tid < 64) {
        int gd = 0;
        while (ldi_agent(ctr + 1) < P_CH) {
            __builtin_amdgcn_s_sleep(2);
            if (++gd > (1 << 16)) break;               // bail out instead of hanging
        }
        int v = (tid < 8) ? ldi_agent(&xcdArr[(b << 3) + tid]) : -1;
        int v0 = __shfl(v, 0, 64);
        bool eq = (tid < 8) ? (v == v0 && v != 0) : true;
        unsigned long long m = __ballot(eq);
        if (tid == 0) sSame = (~m == 0ULL) ? 1 : 0;
    }

    // ---- hoisted per-state constants + LDS init ----
    float lc[4], fc[4];
    #pragma unroll
    for (int i = 0; i < 4; ++i) {
        int s = tid + (i << 9);
        lc[i] = (s < S_DEN) ? DEN_C * den_leaky[s] : 0.f;
        fc[i] = (s < S_DEN) ? den_final[s] : 0.f;
    }
    #pragma unroll
    for (int i = 0; i < 4; ++i) {
        int s = tid + (i << 9);
        alpha[s] = lc[i] + ((s == 0) ? 1.f : 0.f);     // adash0 (asum=1)
        anew[s] = 0.f;
        xrow[s] = expclip(xb[s]);
    }

    // num state (chunk-0 blocks only); edges hoisted into registers.
    float nlk = 0.f, nfn = 0.f, nlogz = 0.f;
    int nein[4], neout[4], nepdf[4]; float neprb[4];
    if (isNum) {
        nlk = num_leaky[(b << 9) + tid];
        nfn = num_final[(b << 9) + tid];
        #pragma unroll
        for (int k = 0; k < 4; ++k) {
            int e = (b << 11) + tid + (k << 9);
            nein[k] = num_in[e]; neout[k] = num_out[e];
            nepdf[k] = num_pdf[e]; neprb[k] = num_prob[e];
        }
        nalpha[tid] = NUM_C * nlk + ((tid == 0) ? 1.f : 0.f);
        nanew[tid] = 0.f;
    }

    // Whole per-thread edge list (16 edges = 8 uint4) lives in registers.
    const uint4* __restrict__ pk4 = (const uint4*)(ws + PACK_OFF);
    const int qb = (p << 12) + (tid << 3);
    const uint4 c0 = pk4[qb + 0], c1 = pk4[qb + 1], c2 = pk4[qb + 2], c3 = pk4[qb + 3];
    const uint4 c4 = pk4[qb + 4], c5 = pk4[qb + 5], c6 = pk4[qb + 6], c7 = pk4[qb + 7];
    const int row0 = ((const int*)(ws + SROW_OFF))[(p << 9) + tid];
    float logz = 0.f;
    __syncthreads();
    const bool fastSt = (sSame != 0);

    for (int t = 0; t < len; ++t) {
        const int par = t & 1;
        // Prefetch x(t+1) into registers (consumed at stage, pre-spin).
        const int tn = (t + 1 < len) ? t + 1 : t;
        const float* xq = xb + (size_t)tn * D_SZ;
        const float xn0 = xq[tid], xn1 = xq[tid + 512];
        const float xn2 = xq[tid + 1024], xn3 = xq[tid + 1536];

        // ---- den edge phase: 16 edges, registers -> LDS gathers ----
        float acc = 0.f, psum = 0.f;
        int row = row0;
        {
            const unsigned w[16] = {c0.x, c0.z, c1.x, c1.z, c2.x, c2.z, c3.x, c3.z,
                                    c4.x, c4.z, c5.x, c5.z, c6.x, c6.z, c7.x, c7.z};
            const unsigned pr[16] = {c0.y, c0.w, c1.y, c1.w, c2.y, c2.w, c3.y, c3.w,
                                     c4.y, c4.w, c5.y, c5.w, c6.y, c6.w, c7.y, c7.w};
            float av[16], xv[16];
            #pragma unroll
            for (int i = 0; i < 16; ++i) av[i] = alpha[w[i] & 2047u];
            #pragma unroll
            for (int i = 0; i < 16; ++i) xv[i] = xrow[(w[i] >> 11) & 2047u];
            #pragma unroll
            for (int i = 0; i < 16; ++i) {
                acc = __fmaf_rn(av[i] * __uint_as_float(pr[i]), xv[i], acc);
                const unsigned d = w[i] >> 22;
                if (d) { psum += acc; atomicAdd(&anew[row], acc); acc = 0.f; row += (int)d; }
            }
        }
        psum += acc;
        if (acc != 0.f) atomicAdd(&anew[row], acc);
        #pragma unroll
        for (int o = 32; o > 0; o >>= 1) psum += __shfl_down(psum, o, 64);
        if (lane == 0) red[tid >> 6] = psum;
        __syncthreads();                         // B1: anew + red complete

        // ---- publish slice + psum; per-wave drain; per-CHUNK arrive ----
        float* ag = anewg + (par << 11);
        const int pidx = ((b << 1) | par) << 4;
        if (tid == 0) {
            float bs = red[0]+red[1]+red[2]+red[3]+red[4]+red[5]+red[6]+red[7];
            if (fastSt) psumg[pidx + p] = bs;
            else        stf_agent(&psumg[pidx + p], bs);
        }
        if (fastSt) {
            for (int r = rlo + tid; r < rhi; r += NTHR) { ag[r] = anew[r]; anew[r] = 0.f; }
        } else {
            for (int r = rlo + tid; r < rhi; r += NTHR) { stf_agent(&ag[r], anew[r]); anew[r] = 0.f; }
        }
        asm volatile("s_waitcnt vmcnt(0)" ::: "memory");  // this wave's stores in L2
        if (lane == 0) {
            int old = atomicAdd(&lcnt, 1);                // monotonic, 8/step
            if (old == 8 * t + 7)                         // last wave of chunk
                __hip_atomic_fetch_add(ctr, 1, __ATOMIC_RELAXED, __HIP_MEMORY_SCOPE_AGENT);
        }

        // ---- num step for this utterance (chunk 0 only; hides in spin window) --
        if (isNum) {
            #pragma unroll
            for (int k = 0; k < 4; ++k) {
                float v = nalpha[nein[k]] * neprb[k] * xrow[nepdf[k]];
                atomicAdd(&nanew[neout[k]], v);
            }
            __syncthreads();                     // Bnum: nanew complete
            float ps = nanew[tid];
            #pragma unroll
            for (int o = 32; o > 0; o >>= 1) ps += __shfl_down(ps, o, 64);
            if (lane == 0) red[8 + (tid >> 6)] = ps;
        }

        // Stage xrow(t+1) while peer chunks finish publishing.
        xrow[tid]        = expclip(xn0);
        xrow[tid + 512]  = expclip(xn1);
        xrow[tid + 1024] = expclip(xn2);
        xrow[tid + 1536] = expclip(xn3);

        // Wave-0 spin on the arrive counter; 8 lanes fetch den psums.
        if (tid < 64) {
            const int target = P_CH * (t + 1);   // 8*(t+1)
            int gd = 0;
            while (ldi_agent(ctr) < target) {
                __builtin_amdgcn_s_sleep(1);
                if (++gd > (1 << 15)) break;     // bail out instead of hanging
            }
            if (tid < 8) red[16 + tid] = ldf_agent(&psumg[pidx + tid]);
        }
        __syncthreads();                         // B2: slices + psums visible

        const float asum = red[16]+red[17]+red[18]+red[19]
                         + red[20]+red[21]+red[22]+red[23];
        const float inv = 1.f / asum;
        // Reload full anew -> adash -> alpha (every block redundantly).
        #pragma unroll
        for (int i = 0; i < 4; ++i) {
            const int s = tid + (i << 9);
            float an = (s < S_DEN) ? ldf_agent(&ag[s]) : 0.f;
            alpha[s] = __fmaf_rn(an, inv, lc[i]);
        }
        logz += logf(asum);
        if (isNum) {
            const float nasum = red[8]+red[9]+red[10]+red[11]
                              + red[12]+red[13]+red[14]+red[15];
            nalpha[tid] = __fmaf_rn(NUM_C * nlk, nasum, nanew[tid]) * (1.f / nasum);
            nanew[tid] = 0.f;
            nlogz += logf(nasum);
        }
        __syncthreads();                         // B3: alpha/xrow ready
    }

    if (isNum) {   // chunk 0: den final dot + num final dot
        float fs = alpha[tid] * fc[0] + alpha[tid + 512] * fc[1]
                 + alpha[tid + 1024] * fc[2] + alpha[tid + 1536] * fc[3];
        #pragma unroll
        for (int o = 32; o > 0; o >>= 1) fs += __shfl_down(fs, o, 64);
        if (lane == 0) red[tid >> 6] = fs;
        __syncthreads();
        if (tid == 0) {
            float tot = red[0]+red[1]+red[2]+red[3]+red[4]+red[5]+red[6]+red[7];
            ((float*)(ws + TOTD_OFF))[b] = logz + logf(tot);
        }
        __syncthreads();
        float nfs = nalpha[tid] * nfn;
        #pragma unroll
        for (int o = 32; o > 0; o >>= 1) nfs += __shfl_down(nfs, o, 64);
        if (lane == 0) red[tid >> 6] = nfs;
        __syncthreads();
        if (tid == 0) {
            float tot = red[0]+red[1]+red[2]+red[3]+red[4]+red[5]+red[6]+red[7];
            ((float*)(ws + TOTN_OFF))[b] = nlogz + logf(tot);
        }
    }
}

__global__ void combine2(const char* __restrict__ ws, const int* __restrict__ lengths,
                         float* __restrict__ out) {
    const float* totd = (const float*)(ws + TOTD_OFF);
    const float* totn = (const float*)(ws + TOTN_OFF);
    int tid = threadIdx.x;
    float v = 0.f, l = 0.f;
    if (tid < B_SZ) { v = totd[tid] - totn[tid]; l = (float)lengths[tid]; }
    #pragma unroll
    for (int o = 32; o > 0; o >>= 1) { v += __shfl_down(v, o, 64); l += __shfl_down(l, o, 64); }
    if (tid == 0) out[0] = v / l;
}

// ===================== round-1 fallback (used only if ws too small) ==========
__global__ __launch_bounds__(1024) void chain_fwd_kernel(
    const float* __restrict__ x, const int* __restrict__ lengths,
    const int* __restrict__ den_in, const int* __restrict__ den_out,
    const int* __restrict__ den_pdf, const float* __restrict__ den_prob,
    const float* __restrict__ den_leaky, const float* __restrict__ den_final,
    const int* __restrict__ num_in, const int* __restrict__ num_out,
    const int* __restrict__ num_pdf, const float* __restrict__ num_prob,
    const float* __restrict__ num_leaky, const float* __restrict__ num_final,
    float* __restrict__ part)
{
    __shared__ float xrow[D_SZ];
    __shared__ float alpha[S_DEN];
    __shared__ float anew[S_DEN];
    __shared__ float red[17];
    const int tid = threadIdx.x;
    const int nthr = 1024;
    const bool is_den = blockIdx.x < B_SZ;
    const int b = blockIdx.x & (B_SZ - 1);
    int S, E;
    const int *e_in, *e_out, *e_pdf;
    const float *e_prob, *leaky, *fin;
    float coeff;
    if (is_den) {
        S = S_DEN; E = E_DEN;
        e_in = den_in; e_out = den_out; e_pdf = den_pdf; e_prob = den_prob;
        leaky = den_leaky; fin = den_final; coeff = DEN_C;
    } else {
        S = S_NUM; E = E_NUM;
        e_in = num_in + b * E_NUM; e_out = num_out + b * E_NUM;
        e_pdf = num_pdf + b * E_NUM; e_prob = num_prob + b * E_NUM;
        leaky = num_leaky + b * S_NUM; fin = num_final + b * S_NUM;
        coeff = NUM_C;
    }
    const int len = lengths[b];
    const float* xb = x + (size_t)b * T_SZ * D_SZ;
    for (int s = tid; s < S; s += nthr)
        alpha[s] = coeff * leaky[s] + (s == 0 ? 1.0f : 0.0f);
    float logz = 0.0f;
    for (int t = 0; t < len; ++t) {
        for (int s = tid; s < S; s += nthr) anew[s] = 0.0f;
        const float* xt = xb + (size_t)t * D_SZ;
        for (int d = tid; d < D_SZ; d += nthr)
            xrow[d] = __expf(fminf(fmaxf(xt[d], -30.0f), 30.0f));
        __syncthreads();
        for (int e = tid; e < E; e += nthr) {
            float v = alpha[e_in[e]] * e_prob[e] * xrow[e_pdf[e]];
            atomicAdd(&anew[e_out[e]], v);
        }
        __syncthreads();
        float ps = 0.0f;
        for (int s = tid; s < S; s += nthr) ps += anew[s];
        #pragma unroll
        for (int off = 32; off > 0; off >>= 1) ps += __shfl_down(ps, off, 64);
        if ((tid & 63) == 0) red[tid >> 6] = ps;
        __syncthreads();
        if (tid < 64) {
            float v = (tid < 16) ? red[tid] : 0.0f;
            #pragma unroll
            for (int off = 8; off > 0; off >>= 1) v += __shfl_down(v, off, 64);
            if (tid == 0) red[16] = v;
        }
        __syncthreads();
        const float asum = red[16];
        const float inv = 1.0f / asum;
        for (int s = tid; s < S; s += nthr)
            alpha[s] = (anew[s] + coeff * leaky[s] * asum) * inv;
        logz += logf(asum);
        __syncthreads();
    }
    float fs = 0.0f;
    for (int s = tid; s < S; s += nthr) fs += alpha[s] * fin[s];
    #pragma unroll
    for (int off = 32; off > 0; off >>= 1) fs += __shfl_down(fs, off, 64);
    if ((tid & 63) == 0) red[tid >> 6] = fs;
    __syncthreads();
    if (tid < 64) {
        float v = (tid < 16) ? red[tid] : 0.0f;
        #pragma unroll
        for (int off = 8; off > 0; off >>= 1) v += __shfl_down(v, off, 64);
        if (tid == 0) part[blockIdx.x] = logz + logf(v);
    }
}

__global__ void combine_kernel(const float* __restrict__ part,
                               const int* __restrict__ lengths,
                               float* __restrict__ out)
{
    int tid = threadIdx.x;
    float v = 0.0f, l = 0.0f;
    if (tid < B_SZ) { v = part[tid] - part[B_SZ + tid]; l = (float)lengths[tid]; }
    #pragma unroll
    for (int off = 32; off > 0; off >>= 1) { v += __shfl_down(v, off, 64); l += __shfl_down(l, off, 64); }
    if (tid == 0) out[0] = v / l;
}

// ---------------------------------------------------------------------------
extern "C" void kernel_launch(void* const* d_in, const int* in_sizes, int n_in,
                              void* d_out, int out_size, void* d_ws, size_t ws_size,
                              hipStream_t stream)
{
    const float* x          = (const float*)d_in[0];
    const int*   lengths    = (const int*)  d_in[1];
    const int*   den_in_p   = (const int*)  d_in[2];
    const int*   den_out_p  = (const int*)  d_in[3];
    const int*   den_pdf_p  = (const int*)  d_in[4];
    const float* den_prob_p = (const float*)d_in[5];
    const float* den_leaky  = (const float*)d_in[6];
    const float* den_final  = (const float*)d_in[7];
    const int*   num_in_p   = (const int*)  d_in[8];
    const int*   num_out_p  = (const int*)  d_in[9];
    const int*   num_pdf_p  = (const int*)  d_in[10];
    const float* num_prob_p = (const float*)d_in[11];
    const float* num_leaky  = (const float*)d_in[12];
    const float* num_final  = (const float*)d_in[13];

    if (ws_size >= WS_BYTES) {
        char* ws = (char*)d_ws;
        hipLaunchKernelGGL(prep_init, dim3(1), dim3(256), 0, stream, ws);
        hipLaunchKernelGGL(prep_hist, dim3((E_DEN + 255) / 256), dim3(256), 0, stream,
                           den_out_p, ws);
        hipLaunchKernelGGL(prep_scan, dim3(1), dim3(1024), 0, stream, ws);
        hipLaunchKernelGGL(prep_scatter, dim3((E_DEN + 255) / 256), dim3(256), 0, stream,
                           den_in_p, den_out_p, den_pdf_p, den_prob_p, ws);
        hipLaunchKernelGGL(prep_pack, dim3((P_CH * EPC + 255) / 256), dim3(256), 0, stream, ws);
        // 56 KB dynamic pad: ~28.2 KB static + 56 KB > 80 KB -> one block/CU;
        // 256 blocks on 256 CUs, all co-resident (spin-safe), private LDS pipes.
        hipLaunchKernelGGL(chain_fwd9, dim3(P_CH * B_SZ), dim3(NTHR), 57344, stream,
                           x, lengths, den_leaky, den_final,
                           num_in_p, num_out_p, num_pdf_p, num_prob_p,
                           num_leaky, num_final, ws);
        hipLaunchKernelGGL(combine2, dim3(1), dim3(64), 0, stream,
                           ws, lengths, (float*)d_out);
    } else {
        float* part = (float*)d_ws;
        hipLaunchKernelGGL(chain_fwd_kernel, dim3(2 * B_SZ), dim3(1024), 0, stream,
                           x, lengths,
                           den_in_p, den_out_p, den_pdf_p, den_prob_p, den_leaky, den_final,
                           num_in_p, num_out_p, num_pdf_p, num_prob_p, num_leaky, num_final,
                           part);
        hipLaunchKernelGGL(combine_kernel, dim3(1), dim3(64), 0, stream,
                           part, lengths, (float*)d_out);
    }
}